// Round 5
// baseline (570.163 us; speedup 1.0000x reference)
//
#include <hip/hip_runtime.h>
#include <stdint.h>

#define NCK 21
// reference: K_EASY = int(200*(1-0.8)) = int(39.9999...) = 39 (Python float trunc!)
#define K_EASY 39
#define K_HARD 160
#define A_TOT  199
#define MARGINF 0.2f

// ws byte offsets
#define OFF_EASY   64
#define OFF_HARD   256
#define OFF_PERA   1024
#define OFF_MINARR 2048
#define OFF_FLAGS1 4096
#define OFF_FLAGS2 135168
#define OFF_ANCH   266240
#define OFF_SIMS   409600

__device__ __forceinline__ unsigned int f2key(float f) {
  unsigned int u = __float_as_uint(f);
  return u ^ ((u & 0x80000000u) ? 0xFFFFFFFFu : 0x80000000u);
}
__device__ __forceinline__ float key2f(unsigned int k) {
  unsigned int u = (k & 0x80000000u) ? (k ^ 0x80000000u) : (k ^ 0xFFFFFFFFu);
  return __uint_as_float(u);
}

// K1: downsampled label/fg byte per pixel + per-block min class -> minArr
__global__ void k_prep(const int* __restrict__ wsss, const int* __restrict__ fsss,
                       unsigned char* __restrict__ flags1, int* __restrict__ minArr) {
  int p = blockIdx.x * 256 + threadIdx.x;           // 0..131071
  int b = p >> 14, r = p & 16383, i = r >> 7, j = r & 127;
  int gi = (b * 512 + i * 4) * 512 + j * 4;
  int w = wsss[gi];
  int f = fsss[gi];
  int fg = (f != 0 && f != 255) ? 1 : 0;
  int wl = (w != 0 && w != 255) ? 1 : 0;
  flags1[p] = (unsigned char)((w & 63) | (fg << 6));
  int cand = wl ? w : NCK;
  for (int off = 32; off > 0; off >>= 1) cand = min(cand, __shfl_down(cand, off));
  __shared__ int wmin[4];
  int lane = threadIdx.x & 63, wid = threadIdx.x >> 6;
  if (lane == 0) wmin[wid] = cand;
  __syncthreads();
  if (threadIdx.x == 0)
    minArr[blockIdx.x] = min(min(wmin[0], wmin[1]), min(wmin[2], wmin[3]));
}

// K2: easy/hard flags. Each block re-reduces minArr (kernel-boundary-ordered,
// L2-hot). Block 0 publishes hdr[0]=cls and zeroes tickets hdr[6..8].
__global__ void k_flags(const float* __restrict__ preds, const unsigned char* __restrict__ flags1,
                        unsigned char* __restrict__ flags2, const int* __restrict__ minArr,
                        int* __restrict__ hdr) {
  int tid = threadIdx.x;
  __shared__ int wm[4];
  __shared__ int s_cls;
  int m = min(minArr[tid], minArr[tid + 256]);
  for (int off = 32; off > 0; off >>= 1) m = min(m, __shfl_down(m, off));
  int lane = tid & 63, wid = tid >> 6;
  if (lane == 0) wm[wid] = m;
  __syncthreads();
  if (tid == 0) {
    int c = min(min(wm[0], wm[1]), min(wm[2], wm[3]));
    s_cls = c;
    if (blockIdx.x == 0) { hdr[0] = c; hdr[6] = 0; hdr[7] = 0; hdr[8] = 0; }
  }
  __syncthreads();
  int cls = s_cls;
  int p = blockIdx.x * 256 + tid;
  unsigned char f1 = flags1[p];
  unsigned char out = 0;
  if ((f1 & 64) && (int)(f1 & 63) == cls) {
    int b = p >> 14, r = p & 16383, i = r >> 7, j = r & 127;
    int base = ((b * NCK) * 512 + i * 4) * 512 + j * 4;
    float best = preds[base]; int bi = 0;
#pragma unroll
    for (int ch = 1; ch < NCK; ++ch) {
      float v = preds[base + ch * 262144];
      if (v > best) { best = v; bi = ch; }
    }
    out = (bi == cls) ? 1 : 2;
  }
  flags2[p] = out;
}

// K3 (fused pick + anchors + sims): 1252 blocks x 256.
// Phase P (block 0, wave 0): ordered pick of 39 easy / 160 hard -> release hdr[7].
// Phase A (blocks 0..63, 4 rows each): anchor gather+normalize -> release hdr[8].
// Phase S (all blocks): 64x64 sims tile, mT=bid%313, aT=bid/313.
// Deadlock-free: producers hold the lowest block IDs; HW dispatches in ID order.
__global__ __launch_bounds__(256) void k_pas(const unsigned char* __restrict__ flags2,
                       int* __restrict__ hdr, int* __restrict__ easy_idx,
                       int* __restrict__ hard_idx, const float* __restrict__ emb,
                       float* __restrict__ anchors, const float* __restrict__ memory,
                       float* __restrict__ sims) {
  int bid = blockIdx.x, tid = threadIdx.x;
  __shared__ float As[64 * 128];
  __shared__ float Ms[64 * 128];

  // ---- Phase P: pick (block 0, lanes 0..63) ----
  if (bid == 0 && tid < 64) {
    int lane = tid;
    const unsigned long long* f8 = (const unsigned long long*)flags2;
    unsigned int runE = 0, runH = 0;
    for (int it4 = 0; it4 < 64; ++it4) {    // 64 * 4 * 64 lanes * 8 B = 131072
      unsigned long long vv0 = f8[(it4 * 4 + 0) * 64 + lane];
      unsigned long long vv1 = f8[(it4 * 4 + 1) * 64 + lane];
      unsigned long long vv2 = f8[(it4 * 4 + 2) * 64 + lane];
      unsigned long long vv3 = f8[(it4 * 4 + 3) * 64 + lane];
#pragma unroll
      for (int q = 0; q < 4; ++q) {
        unsigned long long v = (q == 0) ? vv0 : (q == 1) ? vv1 : (q == 2) ? vv2 : vv3;
        int it = it4 * 4 + q;
        unsigned int e = 0, h = 0;
#pragma unroll
        for (int g = 0; g < 8; ++g) {
          unsigned int b = (unsigned int)((v >> (8 * g)) & 255ull);
          e += (b == 1u); h += (b == 2u);
        }
        unsigned int x = (e << 16) | h;
        unsigned int incl = x;
#pragma unroll
        for (int off = 1; off < 64; off <<= 1) {
          unsigned int t = __shfl_up(incl, off);
          if (lane >= off) incl += t;
        }
        unsigned int excl = incl - x;
        unsigned int eRk = runE + (excl >> 16);
        unsigned int hRk = runH + (excl & 0xFFFFu);
#pragma unroll
        for (int g = 0; g < 8; ++g) {
          unsigned int b = (unsigned int)((v >> (8 * g)) & 255ull);
          int p = it * 512 + lane * 8 + g;
          if (b == 1u)      { if (eRk < K_EASY) easy_idx[eRk] = p; eRk++; }
          else if (b == 2u) { if (hRk < K_HARD) hard_idx[hRk] = p; hRk++; }
        }
        unsigned int tot = __shfl(incl, 63);
        runE += (tot >> 16); runH += (tot & 0xFFFFu);
      }
      if (runE >= K_EASY && runH >= K_HARD) break;   // uniform
    }
    if (lane == 0) {
      int neU = runE < K_EASY ? (int)runE : K_EASY;
      int nhU = runH < K_HARD ? (int)runH : K_HARD;
      hdr[1] = (int)runE; hdr[2] = (int)runH;
      hdr[3] = neU; hdr[4] = nhU; hdr[5] = neU + nhU;
    }
    __threadfence();                     // release idx + hdr[1..5]
    if (lane == 0) atomicExch(&hdr[7], 1);
  }

  // ---- spin: pick done ----
  if (tid == 0) {
    while (atomicAdd(&hdr[7], 0) == 0) __builtin_amdgcn_s_sleep(8);
  }
  __syncthreads();
  __threadfence();                       // acquire
  int nv = hdr[5], neU = hdr[3];

  // ---- Phase A: anchors (blocks 0..63; wave w -> row 4*bid+w) ----
  if (bid < 64) {
    int lane = tid & 63, w = tid >> 6;
    int a = bid * 4 + w;                 // 0..255
    float v0 = 0.f, v1 = 0.f;
    if (a < nv) {
      int p = (a < neU) ? easy_idx[a] : hard_idx[a - neU];
      int b = p >> 14, r = p & 16383, i = r >> 7, j = r & 127;
      int base = b * 2097152 + i * 128 + j;
      v0 = emb[base + lane * 16384];
      v1 = emb[base + (lane + 64) * 16384];
    }
    float ss = v0 * v0 + v1 * v1;
    for (int off = 32; off > 0; off >>= 1) ss += __shfl_xor(ss, off);
    float inv = 1.0f / fmaxf(sqrtf(ss), 1e-12f);
    anchors[a * 128 + lane] = v0 * inv;
    anchors[a * 128 + lane + 64] = v1 * inv;
    __syncthreads();                     // all 4 rows of this block written
    __threadfence();                     // release anchors
    if (tid == 0) atomicAdd(&hdr[8], 1);
  }

  // ---- spin: anchors done ----
  if (tid == 0) {
    while (atomicAdd(&hdr[8], 0) < 64) __builtin_amdgcn_s_sleep(8);
  }
  __syncthreads();
  __threadfence();                       // acquire

  // ---- Phase S: sims 64x64 tile ----
  int mT = bid % 313, aT = bid / 313;
  int aBase = aT * 64, mBase = mT * 64;
#pragma unroll
  for (int k = 0; k < 8; ++k) {   // stage A (swizzled 16B chunks)
    int f4i = tid + k * 256;
    int row = f4i >> 5, c = f4i & 31;
    int gR = aBase + row; if (gR > 255) gR = 255;
    float4 v = ((const float4*)anchors)[gR * 32 + c];
    *(float4*)&As[row * 128 + ((c ^ (row & 31)) << 2)] = v;
  }
#pragma unroll
  for (int k = 0; k < 8; ++k) {   // stage M
    int f4i = tid + k * 256;
    int row = f4i >> 5, c = f4i & 31;
    int grow = mBase + row;
    float4 v = make_float4(0.f, 0.f, 0.f, 0.f);
    if (grow < 20000) v = ((const float4*)memory)[grow * 32 + c];
    *(float4*)&Ms[row * 128 + ((c ^ (row & 31)) << 2)] = v;
  }
  __syncthreads();
  int tx = tid & 15, ty = tid >> 4;
  float acc[4][4];
#pragma unroll
  for (int i = 0; i < 4; ++i)
#pragma unroll
    for (int j = 0; j < 4; ++j) acc[i][j] = 0.f;
#pragma unroll 2
  for (int c = 0; c < 32; ++c) {
    float4 av[4], mv[4];
#pragma unroll
    for (int i = 0; i < 4; ++i) {
      int ar = ty + 16 * i;
      av[i] = *(const float4*)&As[ar * 128 + ((c ^ (ar & 31)) << 2)];
    }
#pragma unroll
    for (int j = 0; j < 4; ++j) {
      int mr = tx + 16 * j;
      mv[j] = *(const float4*)&Ms[mr * 128 + ((c ^ (mr & 31)) << 2)];
    }
#pragma unroll
    for (int i = 0; i < 4; ++i)
#pragma unroll
      for (int j = 0; j < 4; ++j)
        acc[i][j] += av[i].x * mv[j].x + av[i].y * mv[j].y + av[i].z * mv[j].z + av[i].w * mv[j].w;
  }
  __syncthreads();
  {
    int row = tid >> 2, q = tid & 3;
    float ss = 0.f;
#pragma unroll
    for (int k = 0; k < 8; ++k) {
      float4 v = *(const float4*)&Ms[row * 128 + q * 32 + k * 4];
      ss += v.x * v.x + v.y * v.y + v.z * v.z + v.w * v.w;
    }
    ss += __shfl_down(ss, 2, 4);
    ss += __shfl_down(ss, 1, 4);
    if (q == 0) As[row] = 1.0f / fmaxf(sqrtf(ss), 1e-8f);
  }
  __syncthreads();
#pragma unroll
  for (int i = 0; i < 4; ++i) {
    int la = aBase + ty + 16 * i;
    if (la < A_TOT) {
#pragma unroll
      for (int j = 0; j < 4; ++j) {
        int m = mBase + tx + 16 * j;
        if (m < 20000) sims[(size_t)la * 20000 + m] = acc[i][j] * As[tx + 16 * j];
      }
    }
  }
}

// 256-bin suffix-sum + boundary select (wave-0-only, ONE barrier).
__device__ __forceinline__ void suffix_select(unsigned int* histL, unsigned int* sfx,
                                              unsigned int* cnts, int tid, unsigned int krem) {
  if (tid < 64) {
    int lane = tid;
    unsigned int h0 = histL[lane * 4 + 0];
    unsigned int h1 = histL[lane * 4 + 1];
    unsigned int h2 = histL[lane * 4 + 2];
    unsigned int h3 = histL[lane * 4 + 3];
    unsigned int s = h0 + h1 + h2 + h3;
    unsigned int incl = s;                        // sum over lanes >= lane
#pragma unroll
    for (int off = 1; off < 64; off <<= 1) {
      unsigned int t = __shfl_down(incl, off);
      if (lane + off < 64) incl += t;
    }
    unsigned int above = incl - s;                // sum over lanes > lane
    unsigned int f3 = above + h3;
    unsigned int f2 = f3 + h2;
    unsigned int f1 = f2 + h1;
    unsigned int f0 = f1 + h0;
    sfx[lane * 4 + 0] = f0; sfx[lane * 4 + 1] = f1;
    sfx[lane * 4 + 2] = f2; sfx[lane * 4 + 3] = f3;
    if (lane == 63) sfx[256] = 0u;
    if (f0 >= krem && f1 < krem)    cnts[3] = (unsigned int)(lane * 4 + 0);
    if (f1 >= krem && f2 < krem)    cnts[3] = (unsigned int)(lane * 4 + 1);
    if (f2 >= krem && f3 < krem)    cnts[3] = (unsigned int)(lane * 4 + 2);
    if (f3 >= krem && above < krem) cnts[3] = (unsigned int)(lane * 4 + 3);
  }
  __syncthreads();
}

// K6: per-anchor exact top-1000 negatives + pair-loss. 1024 threads (16 waves).
// Fused: (a) doCopy -> grid-strided new_memory write; (b) last-finisher ticket
// on hdr[6] reduces per_anchor -> out[0].
__global__ __launch_bounds__(1024) void k_topk(const float* __restrict__ sims,
                       int* __restrict__ hdr, float* __restrict__ per_anchor,
                       int a0, int ac, float* __restrict__ out,
                       const float* __restrict__ memory, const float* __restrict__ anchors,
                       int doCopy) {
  int tid = threadIdx.x, lane = tid & 63, wid = tid >> 6;
  int nv = hdr[5];
  int cls = hdr[0];

  if (doCopy) {   // fused k_writemem: runs on every block, before any early-out
    int step = gridDim.x * 1024;
    for (int i = blockIdx.x * 1024 + tid; i < 2560000; i += step) {
      float v = memory[i];
      int c = i / 128000;
      int rem = i - c * 128000;
      int m = rem >> 7, d = rem & 127;
      if (cls >= 1 && cls <= 20 && c == cls - 1 && m < nv) v = anchors[m * 128 + d];
      out[1 + i] = v;
    }
    if (nv == 0 && blockIdx.x == 0 && tid == 0) out[0] = 0.f;
  }

  int la = blockIdx.x;
  if (la >= ac) return;
  int a = a0 + la;
  if (a >= nv) return;
  int clsRow = cls - 1;

  __shared__ float posArr[1024];
  __shared__ float qv[1024];
  __shared__ unsigned int hist16[16][256];
  __shared__ unsigned int histL[256];
  __shared__ unsigned int sfx[257];
  __shared__ unsigned int buf[12288];
  __shared__ unsigned int cnts[8];  // 1:bufCnt 2:qvCnt 3:sel 4:levelBufCnt
  __shared__ float fred[16];
  __shared__ unsigned int lastFlag;

  const float* row = sims + (size_t)la * 20000;   // 16B-aligned

  // init
  for (int i = tid; i < 16 * 256; i += 1024) ((unsigned int*)hist16)[i] = 0u;
  if (tid < 24) posArr[1000 + tid] = -1e30f;
  if (tid < 8) cnts[tid] = 0u;
  __syncthreads();

  // P1: per-wave histograms of neg keys' top byte; stash pos row.
  float4 rowq[5];
#pragma unroll
  for (int k = 0; k < 5; ++k) {
    int j = (k << 12) + (tid << 2);
    float4 v = make_float4(0.f, 0.f, 0.f, 0.f);
    if (j < 20000) v = *(const float4*)&row[j];
    rowq[k] = v;
  }
#pragma unroll
  for (int k = 0; k < 5; ++k) {
    int j = (k << 12) + (tid << 2);
    if (j < 20000) {
      int c = j / 1000;
      float4 v = rowq[k];
      if (c == clsRow) {
        *(float4*)&posArr[j - clsRow * 1000] = v;
      } else {
        atomicAdd(&hist16[wid][f2key(v.x) >> 24], 1u);
        atomicAdd(&hist16[wid][f2key(v.y) >> 24], 1u);
        atomicAdd(&hist16[wid][f2key(v.z) >> 24], 1u);
        atomicAdd(&hist16[wid][f2key(v.w) >> 24], 1u);
      }
    }
  }
  __syncthreads();
  if (tid < 256) {
    unsigned int s = 0;
#pragma unroll
    for (int w = 0; w < 16; ++w) s += hist16[w][tid];
    histL[tid] = s;
  }
  __syncthreads();
  suffix_select(histL, sfx, cnts, tid, 1000u);
  unsigned int B0 = cnts[3];
  unsigned int krem = 1000u - sfx[B0 + 1];   // slots to fill from bucket B0
  __syncthreads();

  // P2: compact from registers. top-byte > B0 -> qv; == B0 -> key buf
#pragma unroll
  for (int k = 0; k < 5; ++k) {
    int j = (k << 12) + (tid << 2);
    bool inb = (j < 20000);
    int c = inb ? (j / 1000) : -1;
    bool neg = inb && (c != clsRow);
    float4 v4 = rowq[k];
#pragma unroll
    for (int e = 0; e < 4; ++e) {
      float v = (e == 0) ? v4.x : (e == 1) ? v4.y : (e == 2) ? v4.z : v4.w;
      unsigned int key = f2key(v);
      unsigned int tb = key >> 24;
      bool pq = neg && (tb > B0);
      bool pb = neg && (tb == B0);
      unsigned long long mq = __ballot(pq);
      unsigned long long mb = __ballot(pb);
      unsigned int baseq = 0u, baseb = 0u;
      if (lane == 0) {
        if (mq) baseq = atomicAdd(&cnts[2], (unsigned int)__popcll(mq));
        if (mb) baseb = atomicAdd(&cnts[1], (unsigned int)__popcll(mb));
      }
      baseq = __shfl(baseq, 0); baseb = __shfl(baseb, 0);
      if (pq) qv[baseq + (unsigned int)__popcll(mq & ((1ull << lane) - 1ull))] = v;
      if (pb) {
        unsigned int p = baseb + (unsigned int)__popcll(mb & ((1ull << lane) - 1ull));
        if (p < 12288u) buf[p] = key;
      }
    }
  }
  __syncthreads();
  int ncand = (int)cnts[1];
  bool stored = (ncand <= 12288);

  // P3: three byte-level radix passes for exact threshold key
  unsigned int prefix = B0 << 24;
  for (int level = 0; level < 3; ++level) {
    int shift = 16 - level * 8;
    if (tid < 256) histL[tid] = 0u;
    __syncthreads();
    unsigned int myk[12];             // statically indexed (registers)
    if (stored) {
#pragma unroll
      for (int k = 0; k < 12; ++k) {
        int i = tid + (k << 10);
        if (i < ncand) myk[k] = buf[i];
      }
      __syncthreads();   // all reads done before buf rewrite
#pragma unroll
      for (int k = 0; k < 12; ++k) {
        int i = tid + (k << 10);
        if (i < ncand) atomicAdd(&histL[(myk[k] >> shift) & 255u], 1u);
      }
    } else {
      unsigned int hiMask = 0xFFFFFFFFu << (shift + 8);
      for (int j = tid; j < 20000; j += 1024) {
        int c = j / 1000;
        if (c == clsRow) continue;
        unsigned int key = f2key(row[j]);
        if ((key & hiMask) == prefix) atomicAdd(&histL[(key >> shift) & 255u], 1u);
      }
    }
    __syncthreads();
    suffix_select(histL, sfx, cnts, tid, krem);
    unsigned int bk = cnts[3];
    unsigned int above = sfx[bk + 1];
    krem -= above;
    prefix |= bk << shift;
    if (stored) {
      __syncthreads();
      if (tid == 0) cnts[4] = 0u;
      __syncthreads();
#pragma unroll
      for (int k = 0; k < 12; ++k) {
        int i = tid + (k << 10);
        if (i < ncand) {
          unsigned int b = (myk[k] >> shift) & 255u;
          if (b > bk) qv[atomicAdd(&cnts[2], 1u)] = key2f(myk[k]);
          else if (b == bk) buf[atomicAdd(&cnts[4], 1u)] = myk[k];
        }
      }
      __syncthreads();
      ncand = (int)cnts[4];
    }
  }
  float tval = key2f(prefix);

  if (!stored) {   // fallback: gather all > threshold within bucket B0 from global
    for (int j = tid; j < 20000; j += 1024) {
      int c = j / 1000;
      if (c == clsRow) continue;
      float v = row[j];
      unsigned int key = f2key(v);
      if ((key >> 24) == B0 && key > prefix) qv[atomicAdd(&cnts[2], 1u) & 1023u] = v;
    }
    __syncthreads();
  }
  int qn = (int)cnts[2];          // strictly-greater count, <= 999
  float tieW = (float)krem;       // == 1000 - qn copies of tval

  // P4: one negative per thread; sum relu(pos + margin - neg) over 1024-padded pos
  float v, w;
  if (tid < qn)       { v = qv[tid]; w = 1.f; }
  else if (tid == qn) { v = tval;    w = tieW; }
  else                { v = 0.f;     w = 0.f; }
  float t = v - MARGINF;
  float s0 = 0.f, s1 = 0.f, s2 = 0.f, s3 = 0.f;
  if (w != 0.f) {
    for (int pc = 0; pc < 1024; pc += 16) {
      float4 p0 = *(const float4*)&posArr[pc];
      float4 p1 = *(const float4*)&posArr[pc + 4];
      float4 p2 = *(const float4*)&posArr[pc + 8];
      float4 p3 = *(const float4*)&posArr[pc + 12];
      s0 += fmaxf(p0.x - t, 0.f); s1 += fmaxf(p0.y - t, 0.f);
      s2 += fmaxf(p0.z - t, 0.f); s3 += fmaxf(p0.w - t, 0.f);
      s0 += fmaxf(p1.x - t, 0.f); s1 += fmaxf(p1.y - t, 0.f);
      s2 += fmaxf(p1.z - t, 0.f); s3 += fmaxf(p1.w - t, 0.f);
      s0 += fmaxf(p2.x - t, 0.f); s1 += fmaxf(p2.y - t, 0.f);
      s2 += fmaxf(p2.z - t, 0.f); s3 += fmaxf(p2.w - t, 0.f);
      s0 += fmaxf(p3.x - t, 0.f); s1 += fmaxf(p3.y - t, 0.f);
      s2 += fmaxf(p3.z - t, 0.f); s3 += fmaxf(p3.w - t, 0.f);
    }
  }
  float local = w * ((s0 + s1) + (s2 + s3));
  for (int off = 32; off; off >>= 1) local += __shfl_down(local, off);
  if (lane == 0) fred[wid] = local;
  __syncthreads();
  if (tid == 0) {
    float s = 0.f;
#pragma unroll
    for (int i = 0; i < 16; ++i) s += fred[i];
    per_anchor[a] = s * 1e-6f;
    __threadfence();
    unsigned int tk = atomicAdd((unsigned int*)&hdr[6], 1u);
    lastFlag = (tk == (unsigned int)(nv - 1)) ? 1u : 0u;
  }
  __syncthreads();
  if (lastFlag) {
    __threadfence();   // acquire: all blocks' per_anchor stores visible
    float s = (tid < nv) ? per_anchor[tid] : 0.f;
    for (int off = 32; off; off >>= 1) s += __shfl_down(s, off);
    if (lane == 0) fred[wid] = s;
    __syncthreads();
    if (tid == 0) {
      float tot = 0.f;
#pragma unroll
      for (int i = 0; i < 16; ++i) tot += fred[i];
      out[0] = tot / (float)max(nv, 1);
    }
  }
}

// ---- fallback-only kernels (small ws; never taken at ws=704MB) ----
__global__ void k_pick(const unsigned char* __restrict__ flags2, int* __restrict__ hdr,
                       int* __restrict__ easy_idx, int* __restrict__ hard_idx) {
  int lane = threadIdx.x;
  const unsigned long long* f8 = (const unsigned long long*)flags2;
  unsigned int runE = 0, runH = 0;
  for (int it = 0; it < 256; ++it) {
    unsigned long long v = f8[it * 64 + lane];
    unsigned int e = 0, h = 0;
#pragma unroll
    for (int g = 0; g < 8; ++g) {
      unsigned int b = (unsigned int)((v >> (8 * g)) & 255ull);
      e += (b == 1u); h += (b == 2u);
    }
    unsigned int x = (e << 16) | h;
    unsigned int incl = x;
#pragma unroll
    for (int off = 1; off < 64; off <<= 1) {
      unsigned int t = __shfl_up(incl, off);
      if (lane >= off) incl += t;
    }
    unsigned int excl = incl - x;
    unsigned int eRk = runE + (excl >> 16);
    unsigned int hRk = runH + (excl & 0xFFFFu);
#pragma unroll
    for (int g = 0; g < 8; ++g) {
      unsigned int b = (unsigned int)((v >> (8 * g)) & 255ull);
      int p = it * 512 + lane * 8 + g;
      if (b == 1u)      { if (eRk < K_EASY) easy_idx[eRk] = p; eRk++; }
      else if (b == 2u) { if (hRk < K_HARD) hard_idx[hRk] = p; hRk++; }
    }
    unsigned int tot = __shfl(incl, 63);
    runE += (tot >> 16); runH += (tot & 0xFFFFu);
    if (runE >= K_EASY && runH >= K_HARD) break;
  }
  if (lane == 0) {
    int neU = runE < K_EASY ? (int)runE : K_EASY;
    int nhU = runH < K_HARD ? (int)runH : K_HARD;
    hdr[1] = (int)runE; hdr[2] = (int)runH;
    hdr[3] = neU; hdr[4] = nhU; hdr[5] = neU + nhU;
  }
}

__global__ void k_anchors(const float* __restrict__ emb, const int* __restrict__ hdr,
                          const int* __restrict__ easy_idx, const int* __restrict__ hard_idx,
                          float* __restrict__ anchors) {
  int a = blockIdx.x;
  int tid = threadIdx.x;
  int nv = hdr[5], neU = hdr[3];
  float v0 = 0.f, v1 = 0.f;
  if (a < nv) {
    int p = (a < neU) ? easy_idx[a] : hard_idx[a - neU];
    int b = p >> 14, r = p & 16383, i = r >> 7, j = r & 127;
    int base = b * 2097152 + i * 128 + j;
    v0 = emb[base + tid * 16384];
    v1 = emb[base + (tid + 64) * 16384];
  }
  float ss = v0 * v0 + v1 * v1;
  for (int off = 32; off > 0; off >>= 1) ss += __shfl_xor(ss, off);
  float inv = 1.0f / fmaxf(sqrtf(ss), 1e-12f);
  anchors[a * 128 + tid] = v0 * inv;
  anchors[a * 128 + tid + 64] = v1 * inv;
}

__global__ __launch_bounds__(256) void k_sims(const float* __restrict__ anchors,
                       const float* __restrict__ memory, float* __restrict__ sims,
                       int a0, int ac) {
  __shared__ float As[64 * 128];
  __shared__ float Ms[64 * 128];
  int mT = blockIdx.x, aT = blockIdx.y;
  int aBase = aT * 64, mBase = mT * 64;
  int tid = threadIdx.x;
#pragma unroll
  for (int k = 0; k < 8; ++k) {
    int f4i = tid + k * 256;
    int row = f4i >> 5, c = f4i & 31;
    int gR = a0 + aBase + row; if (gR > 255) gR = 255;
    float4 v = ((const float4*)anchors)[gR * 32 + c];
    *(float4*)&As[row * 128 + ((c ^ (row & 31)) << 2)] = v;
  }
#pragma unroll
  for (int k = 0; k < 8; ++k) {
    int f4i = tid + k * 256;
    int row = f4i >> 5, c = f4i & 31;
    int grow = mBase + row;
    float4 v = make_float4(0.f, 0.f, 0.f, 0.f);
    if (grow < 20000) v = ((const float4*)memory)[grow * 32 + c];
    *(float4*)&Ms[row * 128 + ((c ^ (row & 31)) << 2)] = v;
  }
  __syncthreads();
  int tx = tid & 15, ty = tid >> 4;
  float acc[4][4];
#pragma unroll
  for (int i = 0; i < 4; ++i)
#pragma unroll
    for (int j = 0; j < 4; ++j) acc[i][j] = 0.f;
#pragma unroll 2
  for (int c = 0; c < 32; ++c) {
    float4 av[4], mv[4];
#pragma unroll
    for (int i = 0; i < 4; ++i) {
      int ar = ty + 16 * i;
      av[i] = *(const float4*)&As[ar * 128 + ((c ^ (ar & 31)) << 2)];
    }
#pragma unroll
    for (int j = 0; j < 4; ++j) {
      int mr = tx + 16 * j;
      mv[j] = *(const float4*)&Ms[mr * 128 + ((c ^ (mr & 31)) << 2)];
    }
#pragma unroll
    for (int i = 0; i < 4; ++i)
#pragma unroll
      for (int j = 0; j < 4; ++j)
        acc[i][j] += av[i].x * mv[j].x + av[i].y * mv[j].y + av[i].z * mv[j].z + av[i].w * mv[j].w;
  }
  __syncthreads();
  {
    int row = tid >> 2, q = tid & 3;
    float ss = 0.f;
#pragma unroll
    for (int k = 0; k < 8; ++k) {
      float4 v = *(const float4*)&Ms[row * 128 + q * 32 + k * 4];
      ss += v.x * v.x + v.y * v.y + v.z * v.z + v.w * v.w;
    }
    ss += __shfl_down(ss, 2, 4);
    ss += __shfl_down(ss, 1, 4);
    if (q == 0) As[row] = 1.0f / fmaxf(sqrtf(ss), 1e-8f);
  }
  __syncthreads();
#pragma unroll
  for (int i = 0; i < 4; ++i) {
    int la = aBase + ty + 16 * i;
    if (la < ac) {
#pragma unroll
      for (int j = 0; j < 4; ++j) {
        int m = mBase + tx + 16 * j;
        if (m < 20000) sims[(size_t)la * 20000 + m] = acc[i][j] * As[tx + 16 * j];
      }
    }
  }
}

__global__ void k_writemem(const float* __restrict__ memory, const float* __restrict__ anchors,
                           const int* __restrict__ hdr, float* __restrict__ out) {
  int cls = hdr[0], nv = hdr[5];
  if (nv == 0 && blockIdx.x == 0 && threadIdx.x == 0) out[0] = 0.f;
  int i = blockIdx.x * 1024 + threadIdx.x;
#pragma unroll
  for (int k = 0; k < 4; ++k, i += 256) {
    float v = memory[i];
    int c = i / 128000;
    int rem = i - c * 128000;
    int m = rem >> 7, d = rem & 127;
    if (cls >= 1 && cls <= 20 && c == cls - 1 && m < nv) v = anchors[m * 128 + d];
    out[1 + i] = v;
  }
}

extern "C" void kernel_launch(void* const* d_in, const int* in_sizes, int n_in,
                              void* d_out, int out_size, void* d_ws, size_t ws_size,
                              hipStream_t stream) {
  const float* preds  = (const float*)d_in[0];
  const float* emb    = (const float*)d_in[1];
  const int*   wsss   = (const int*)d_in[2];
  const int*   fsss   = (const int*)d_in[3];
  const float* memory = (const float*)d_in[4];
  float* out = (float*)d_out;
  char* ws = (char*)d_ws;
  int* hdr = (int*)ws;
  int* easy_idx = (int*)(ws + OFF_EASY);
  int* hard_idx = (int*)(ws + OFF_HARD);
  float* per_anchor = (float*)(ws + OFF_PERA);
  int* minArr = (int*)(ws + OFF_MINARR);
  unsigned char* flags1 = (unsigned char*)(ws + OFF_FLAGS1);
  unsigned char* flags2 = (unsigned char*)(ws + OFF_FLAGS2);
  float* anchors = (float*)(ws + OFF_ANCH);
  float* sims = (float*)(ws + OFF_SIMS);

  hipLaunchKernelGGL(k_prep,  dim3(512), dim3(256), 0, stream, wsss, fsss, flags1, minArr);
  hipLaunchKernelGGL(k_flags, dim3(512), dim3(256), 0, stream, preds, flags1, flags2, minArr, hdr);

  long long avail = (long long)ws_size - (long long)OFF_SIMS;
  int capWs = (avail > 0) ? (int)(avail / 80000LL) : 0;
  if (capWs > A_TOT) capWs = A_TOT;

  if (capWs >= A_TOT) {
    // fast path: 4 dispatches total (prep, flags, pas, topk)
    hipLaunchKernelGGL(k_pas, dim3(1252), dim3(256), 0, stream, flags2, hdr,
                       easy_idx, hard_idx, emb, anchors, memory, sims);
    hipLaunchKernelGGL(k_topk, dim3(A_TOT), dim3(1024), 0, stream, sims, hdr, per_anchor,
                       0, A_TOT, out, memory, anchors, 1);
  } else {
    // fallback: chunked sims via out-buffer scratch (out+4, 16B-aligned)
    hipLaunchKernelGGL(k_pick,    dim3(1),   dim3(64), 0, stream, flags2, hdr, easy_idx, hard_idx);
    hipLaunchKernelGGL(k_anchors, dim3(256), dim3(64), 0, stream, emb, hdr, easy_idx, hard_idx, anchors);
    float* outScr = out + 4;
    int capOut = (int)(((long long)out_size / 4 - 4) / 20000LL);
    if (capOut > 127) capOut = 127;
    if (capOut < 0) capOut = 0;
    if (capOut + capWs < 1) capWs = 1;
    int aoff = 0;
    while (aoff < A_TOT) {
      int nOut = A_TOT - aoff; if (nOut > capOut) nOut = capOut;
      int nWs  = A_TOT - aoff - nOut; if (nWs > capWs) nWs = capWs;
      if (nOut > 0) {
        dim3 g1(313, (nOut + 63) / 64);
        hipLaunchKernelGGL(k_sims, g1, dim3(256), 0, stream, anchors, memory, outScr, aoff, nOut);
      }
      if (nWs > 0) {
        dim3 g2(313, (nWs + 63) / 64);
        hipLaunchKernelGGL(k_sims, g2, dim3(256), 0, stream, anchors, memory, sims, aoff + nOut, nWs);
      }
      if (nOut > 0)
        hipLaunchKernelGGL(k_topk, dim3(nOut), dim3(1024), 0, stream, outScr, hdr, per_anchor,
                           aoff, nOut, out, memory, anchors, 0);
      if (nWs > 0)
        hipLaunchKernelGGL(k_topk, dim3(nWs), dim3(1024), 0, stream, sims, hdr, per_anchor,
                           aoff + nOut, nWs, out, memory, anchors, 0);
      aoff += nOut + nWs;
    }
    hipLaunchKernelGGL(k_writemem, dim3(2500), dim3(256), 0, stream, memory, anchors, hdr, out);
  }
}

// Round 8
// 421.323 us; speedup vs baseline: 1.3533x; 1.3533x over previous
//
#include <hip/hip_runtime.h>
#include <stdint.h>

#define NCK 21
// reference: K_EASY = int(200*(1-0.8)) = int(39.9999...) = 39 (Python float trunc!)
#define K_EASY 39
#define K_HARD 160
#define A_TOT  199
#define MARGINF 0.2f

// ws byte offsets
#define OFF_EASY   64
#define OFF_HARD   256
#define OFF_PERA   1024
#define OFF_MINARR 2048
#define OFF_FL     4096      // ushort[131072] = 256 KiB, ends at 266240
#define OFF_ANCH   266240    // float[256*128] = 128 KiB
#define OFF_SIMS   409600

__device__ __forceinline__ unsigned int f2key(float f) {
  unsigned int u = __float_as_uint(f);
  return u ^ ((u & 0x80000000u) ? 0xFFFFFFFFu : 0x80000000u);
}
__device__ __forceinline__ float key2f(unsigned int k) {
  unsigned int u = (k & 0x80000000u) ? (k ^ 0x80000000u) : (k ^ 0xFFFFFFFFu);
  return __uint_as_float(u);
}

// K1: per-pixel ushort record (label | fg<<6 | argmax<<8) + per-block min class.
// Argmax over 21 channels computed unconditionally (removes the k_flags kernel).
// Traffic: all 128B lines of sampled rows fetched at 1/4 use = 44 MB ~ 7us.
__global__ void k_prep(const int* __restrict__ wsss, const int* __restrict__ fsss,
                       const float* __restrict__ preds,
                       unsigned short* __restrict__ fl, int* __restrict__ minArr) {
  int p = blockIdx.x * 256 + threadIdx.x;           // 0..131071
  int b = p >> 14, r = p & 16383, i = r >> 7, j = r & 127;
  int gi = (b * 512 + i * 4) * 512 + j * 4;
  int w = wsss[gi];
  int f = fsss[gi];
  int fg = (f != 0 && f != 255) ? 1 : 0;
  int wl = (w != 0 && w != 255) ? 1 : 0;
  int base = ((b * NCK) * 512 + i * 4) * 512 + j * 4;
  float best = preds[base]; int bi = 0;
#pragma unroll
  for (int ch = 1; ch < NCK; ++ch) {
    float v = preds[base + ch * 262144];
    if (v > best) { best = v; bi = ch; }
  }
  fl[p] = (unsigned short)((w & 63) | (fg << 6) | (bi << 8));
  int cand = wl ? w : NCK;
  for (int off = 32; off > 0; off >>= 1) cand = min(cand, __shfl_down(cand, off));
  __shared__ int wmin[4];
  int lane = threadIdx.x & 63, wid = threadIdx.x >> 6;
  if (lane == 0) wmin[wid] = cand;
  __syncthreads();
  if (threadIdx.x == 0)
    minArr[blockIdx.x] = min(min(wmin[0], wmin[1]), min(wmin[2], wmin[3]));
}

// K2 (single block, 1024 threads): cls reduce -> pick scan (wave 0) -> anchors.
// All cross-phase deps are intra-block __syncthreads() — NO cross-block spin
// (round-5 lesson: contended-atomic spin barriers cost ~280us on this chip).
__global__ __launch_bounds__(1024) void k_pa(const unsigned short* __restrict__ fl,
                       const int* __restrict__ minArr, int* __restrict__ hdr,
                       int* __restrict__ easy_idx, int* __restrict__ hard_idx,
                       const float* __restrict__ emb, float* __restrict__ anchors) {
  int tid = threadIdx.x;
  __shared__ int red[16];
  __shared__ int s_cls, s_neU, s_nv;

  // Phase 0: global min class from minArr[512]
  int m = NCK;
  if (tid < 512) m = minArr[tid];
  for (int off = 32; off > 0; off >>= 1) m = min(m, __shfl_down(m, off));
  if ((tid & 63) == 0) red[tid >> 6] = m;
  __syncthreads();
  if (tid == 0) {
    int c = red[0];
#pragma unroll
    for (int i = 1; i < 16; ++i) c = min(c, red[i]);
    s_cls = c;
    hdr[0] = c;
    hdr[6] = 0;          // loss ticket for k_topk
  }
  __syncthreads();
  int cls = s_cls;

  // Phase 1: ordered pick of first 39 easy / 160 hard (wave 0 only)
  if (tid < 64) {
    int lane = tid;
    const unsigned long long* f8 = (const unsigned long long*)fl;
    unsigned int runE = 0, runH = 0;
    for (int it2 = 0; it2 < 128; ++it2) {    // 128 * 2 its * 512 px = 131072
      unsigned long long A0 = f8[(it2 * 2 + 0) * 128 + lane * 2];
      unsigned long long A1 = f8[(it2 * 2 + 0) * 128 + lane * 2 + 1];
      unsigned long long B0 = f8[(it2 * 2 + 1) * 128 + lane * 2];
      unsigned long long B1 = f8[(it2 * 2 + 1) * 128 + lane * 2 + 1];
#pragma unroll
      for (int q = 0; q < 2; ++q) {
        unsigned long long lo = q ? B0 : A0;
        unsigned long long hi = q ? B1 : A1;
        int it = it2 * 2 + q;
        unsigned int e = 0, h = 0, eb = 0, hb = 0;
#pragma unroll
        for (int g = 0; g < 8; ++g) {
          unsigned int u = (unsigned int)(((g < 4 ? lo : hi) >> (16 * (g & 3))) & 0xFFFFull);
          int lbl = u & 63, fgb = u & 64, am = (u >> 8) & 31;
          bool anc = fgb && (lbl == cls);
          bool ee = anc && (am == cls);
          bool hh = anc && (am != cls);
          e += ee; h += hh;
          eb |= (ee ? 1u : 0u) << g; hb |= (hh ? 1u : 0u) << g;
        }
        unsigned int x = (e << 16) | h;
        unsigned int incl = x;
#pragma unroll
        for (int off = 1; off < 64; off <<= 1) {
          unsigned int t = __shfl_up(incl, off);
          if (lane >= off) incl += t;
        }
        unsigned int excl = incl - x;
        unsigned int eRk = runE + (excl >> 16);
        unsigned int hRk = runH + (excl & 0xFFFFu);
#pragma unroll
        for (int g = 0; g < 8; ++g) {
          int p = it * 512 + lane * 8 + g;
          if ((eb >> g) & 1u)      { if (eRk < K_EASY) easy_idx[eRk] = p; eRk++; }
          else if ((hb >> g) & 1u) { if (hRk < K_HARD) hard_idx[hRk] = p; hRk++; }
        }
        unsigned int tot = __shfl(incl, 63);
        runE += (tot >> 16); runH += (tot & 0xFFFFu);
      }
      if (runE >= K_EASY && runH >= K_HARD) break;   // uniform
    }
    if (lane == 0) {
      int neU = runE < K_EASY ? (int)runE : K_EASY;
      int nhU = runH < K_HARD ? (int)runH : K_HARD;
      hdr[1] = (int)runE; hdr[2] = (int)runH;
      hdr[3] = neU; hdr[4] = nhU; hdr[5] = neU + nhU;
      s_neU = neU; s_nv = neU + nhU;
    }
  }
  __syncthreads();   // idx[] global writes visible block-wide; s_neU/s_nv ready
  int nv = s_nv, neU = s_neU;

  // Phase 2: anchors — 16 waves, 2 rows in flight per wave (256 rows total)
  int lane = tid & 63, w = tid >> 6;
  for (int rr = 0; rr < 8; ++rr) {
    int a0 = rr * 32 + w;        // 0..255 over rr,w
    int a1 = a0 + 16;
    float u0 = 0.f, u1 = 0.f, v0 = 0.f, v1 = 0.f;
    if (a0 < nv) {
      int p = (a0 < neU) ? easy_idx[a0] : hard_idx[a0 - neU];
      int b = p >> 14, r = p & 16383, i = r >> 7, j = r & 127;
      int base = b * 2097152 + i * 128 + j;
      u0 = emb[base + lane * 16384];
      u1 = emb[base + (lane + 64) * 16384];
    }
    if (a1 < nv) {
      int p = (a1 < neU) ? easy_idx[a1] : hard_idx[a1 - neU];
      int b = p >> 14, r = p & 16383, i = r >> 7, j = r & 127;
      int base = b * 2097152 + i * 128 + j;
      v0 = emb[base + lane * 16384];
      v1 = emb[base + (lane + 64) * 16384];
    }
    float ss0 = u0 * u0 + u1 * u1;
    float ss1 = v0 * v0 + v1 * v1;
    for (int off = 32; off > 0; off >>= 1) {
      ss0 += __shfl_xor(ss0, off);
      ss1 += __shfl_xor(ss1, off);
    }
    float inv0 = 1.0f / fmaxf(sqrtf(ss0), 1e-12f);
    float inv1 = 1.0f / fmaxf(sqrtf(ss1), 1e-12f);
    anchors[a0 * 128 + lane] = u0 * inv0;
    anchors[a0 * 128 + lane + 64] = u1 * inv0;
    anchors[a1 * 128 + lane] = v0 * inv1;
    anchors[a1 * 128 + lane + 64] = v1 * inv1;
  }
}

// K5: sims[la][cm] = dot(anchor_{a0+la}, mem_row_cm) * invnorm(mem_row). 64x64 tiles.
__global__ __launch_bounds__(256) void k_sims(const float* __restrict__ anchors,
                       const float* __restrict__ memory, float* __restrict__ sims,
                       int a0, int ac) {
  __shared__ float As[64 * 128];
  __shared__ float Ms[64 * 128];
  int mT = blockIdx.x, aT = blockIdx.y;
  int aBase = aT * 64, mBase = mT * 64;
  int tid = threadIdx.x;
#pragma unroll
  for (int k = 0; k < 8; ++k) {   // stage A (swizzled 16B chunks)
    int f4i = tid + k * 256;
    int row = f4i >> 5, c = f4i & 31;
    int gR = a0 + aBase + row; if (gR > 255) gR = 255;
    float4 v = ((const float4*)anchors)[gR * 32 + c];
    *(float4*)&As[row * 128 + ((c ^ (row & 31)) << 2)] = v;
  }
#pragma unroll
  for (int k = 0; k < 8; ++k) {   // stage M
    int f4i = tid + k * 256;
    int row = f4i >> 5, c = f4i & 31;
    int grow = mBase + row;
    float4 v = make_float4(0.f, 0.f, 0.f, 0.f);
    if (grow < 20000) v = ((const float4*)memory)[grow * 32 + c];
    *(float4*)&Ms[row * 128 + ((c ^ (row & 31)) << 2)] = v;
  }
  __syncthreads();
  int tx = tid & 15, ty = tid >> 4;
  float acc[4][4];
#pragma unroll
  for (int i = 0; i < 4; ++i)
#pragma unroll
    for (int j = 0; j < 4; ++j) acc[i][j] = 0.f;
#pragma unroll 2
  for (int c = 0; c < 32; ++c) {
    float4 av[4], mv[4];
#pragma unroll
    for (int i = 0; i < 4; ++i) {
      int ar = ty + 16 * i;
      av[i] = *(const float4*)&As[ar * 128 + ((c ^ (ar & 31)) << 2)];
    }
#pragma unroll
    for (int j = 0; j < 4; ++j) {
      int mr = tx + 16 * j;
      mv[j] = *(const float4*)&Ms[mr * 128 + ((c ^ (mr & 31)) << 2)];
    }
#pragma unroll
    for (int i = 0; i < 4; ++i)
#pragma unroll
      for (int j = 0; j < 4; ++j)
        acc[i][j] += av[i].x * mv[j].x + av[i].y * mv[j].y + av[i].z * mv[j].z + av[i].w * mv[j].w;
  }
  __syncthreads();
  {
    int row = tid >> 2, q = tid & 3;
    float ss = 0.f;
#pragma unroll
    for (int k = 0; k < 8; ++k) {
      float4 v = *(const float4*)&Ms[row * 128 + q * 32 + k * 4];
      ss += v.x * v.x + v.y * v.y + v.z * v.z + v.w * v.w;
    }
    ss += __shfl_down(ss, 2, 4);
    ss += __shfl_down(ss, 1, 4);
    if (q == 0) As[row] = 1.0f / fmaxf(sqrtf(ss), 1e-8f);
  }
  __syncthreads();
#pragma unroll
  for (int i = 0; i < 4; ++i) {
    int la = aBase + ty + 16 * i;
    if (la < ac) {
#pragma unroll
      for (int j = 0; j < 4; ++j) {
        int m = mBase + tx + 16 * j;
        if (m < 20000) sims[(size_t)la * 20000 + m] = acc[i][j] * As[tx + 16 * j];
      }
    }
  }
}

// 256-bin suffix-sum + boundary select (wave-0-only, ONE barrier).
__device__ __forceinline__ void suffix_select(unsigned int* histL, unsigned int* sfx,
                                              unsigned int* cnts, int tid, unsigned int krem) {
  if (tid < 64) {
    int lane = tid;
    unsigned int h0 = histL[lane * 4 + 0];
    unsigned int h1 = histL[lane * 4 + 1];
    unsigned int h2 = histL[lane * 4 + 2];
    unsigned int h3 = histL[lane * 4 + 3];
    unsigned int s = h0 + h1 + h2 + h3;
    unsigned int incl = s;                        // sum over lanes >= lane
#pragma unroll
    for (int off = 1; off < 64; off <<= 1) {
      unsigned int t = __shfl_down(incl, off);
      if (lane + off < 64) incl += t;
    }
    unsigned int above = incl - s;                // sum over lanes > lane
    unsigned int f3 = above + h3;
    unsigned int f2 = f3 + h2;
    unsigned int f1 = f2 + h1;
    unsigned int f0 = f1 + h0;
    sfx[lane * 4 + 0] = f0; sfx[lane * 4 + 1] = f1;
    sfx[lane * 4 + 2] = f2; sfx[lane * 4 + 3] = f3;
    if (lane == 63) sfx[256] = 0u;
    if (f0 >= krem && f1 < krem)    cnts[3] = (unsigned int)(lane * 4 + 0);
    if (f1 >= krem && f2 < krem)    cnts[3] = (unsigned int)(lane * 4 + 1);
    if (f2 >= krem && f3 < krem)    cnts[3] = (unsigned int)(lane * 4 + 2);
    if (f3 >= krem && above < krem) cnts[3] = (unsigned int)(lane * 4 + 3);
  }
  __syncthreads();
}

// K6: per-anchor exact top-1000 negatives + pair-loss. 1024 threads (16 waves).
// Fused: (a) doCopy -> grid-strided new_memory write; (b) last-finisher ticket
// on hdr[6] reduces per_anchor -> out[0].
__global__ __launch_bounds__(1024) void k_topk(const float* __restrict__ sims,
                       int* __restrict__ hdr, float* __restrict__ per_anchor,
                       int a0, int ac, float* __restrict__ out,
                       const float* __restrict__ memory, const float* __restrict__ anchors,
                       int doCopy) {
  int tid = threadIdx.x, lane = tid & 63, wid = tid >> 6;
  int nv = hdr[5];
  int cls = hdr[0];

  if (doCopy) {   // fused k_writemem: runs on every block, before any early-out
    int step = gridDim.x * 1024;
    for (int i = blockIdx.x * 1024 + tid; i < 2560000; i += step) {
      float v = memory[i];
      int c = i / 128000;
      int rem = i - c * 128000;
      int m = rem >> 7, d = rem & 127;
      if (cls >= 1 && cls <= 20 && c == cls - 1 && m < nv) v = anchors[m * 128 + d];
      out[1 + i] = v;
    }
    if (nv == 0 && blockIdx.x == 0 && tid == 0) out[0] = 0.f;
  }

  int la = blockIdx.x;
  if (la >= ac) return;
  int a = a0 + la;
  if (a >= nv) return;
  int clsRow = cls - 1;

  __shared__ float posArr[1024];
  __shared__ float qv[1024];
  __shared__ unsigned int hist16[16][256];
  __shared__ unsigned int histL[256];
  __shared__ unsigned int sfx[257];
  __shared__ unsigned int buf[12288];
  __shared__ unsigned int cnts[8];  // 1:bufCnt 2:qvCnt 3:sel 4:levelBufCnt
  __shared__ float fred[16];
  __shared__ unsigned int lastFlag;

  const float* row = sims + (size_t)la * 20000;   // 16B-aligned

  // init
  for (int i = tid; i < 16 * 256; i += 1024) ((unsigned int*)hist16)[i] = 0u;
  if (tid < 24) posArr[1000 + tid] = -1e30f;
  if (tid < 8) cnts[tid] = 0u;
  __syncthreads();

  // P1: per-wave histograms of neg keys' top byte; stash pos row.
  float4 rowq[5];
#pragma unroll
  for (int k = 0; k < 5; ++k) {
    int j = (k << 12) + (tid << 2);
    float4 v = make_float4(0.f, 0.f, 0.f, 0.f);
    if (j < 20000) v = *(const float4*)&row[j];
    rowq[k] = v;
  }
#pragma unroll
  for (int k = 0; k < 5; ++k) {
    int j = (k << 12) + (tid << 2);
    if (j < 20000) {
      int c = j / 1000;
      float4 v = rowq[k];
      if (c == clsRow) {
        *(float4*)&posArr[j - clsRow * 1000] = v;
      } else {
        atomicAdd(&hist16[wid][f2key(v.x) >> 24], 1u);
        atomicAdd(&hist16[wid][f2key(v.y) >> 24], 1u);
        atomicAdd(&hist16[wid][f2key(v.z) >> 24], 1u);
        atomicAdd(&hist16[wid][f2key(v.w) >> 24], 1u);
      }
    }
  }
  __syncthreads();
  if (tid < 256) {
    unsigned int s = 0;
#pragma unroll
    for (int w = 0; w < 16; ++w) s += hist16[w][tid];
    histL[tid] = s;
  }
  __syncthreads();
  suffix_select(histL, sfx, cnts, tid, 1000u);
  unsigned int B0 = cnts[3];
  unsigned int krem = 1000u - sfx[B0 + 1];   // slots to fill from bucket B0
  __syncthreads();

  // P2: compact from registers. top-byte > B0 -> qv; == B0 -> key buf
#pragma unroll
  for (int k = 0; k < 5; ++k) {
    int j = (k << 12) + (tid << 2);
    bool inb = (j < 20000);
    int c = inb ? (j / 1000) : -1;
    bool neg = inb && (c != clsRow);
    float4 v4 = rowq[k];
#pragma unroll
    for (int e = 0; e < 4; ++e) {
      float v = (e == 0) ? v4.x : (e == 1) ? v4.y : (e == 2) ? v4.z : v4.w;
      unsigned int key = f2key(v);
      unsigned int tb = key >> 24;
      bool pq = neg && (tb > B0);
      bool pb = neg && (tb == B0);
      unsigned long long mq = __ballot(pq);
      unsigned long long mb = __ballot(pb);
      unsigned int baseq = 0u, baseb = 0u;
      if (lane == 0) {
        if (mq) baseq = atomicAdd(&cnts[2], (unsigned int)__popcll(mq));
        if (mb) baseb = atomicAdd(&cnts[1], (unsigned int)__popcll(mb));
      }
      baseq = __shfl(baseq, 0); baseb = __shfl(baseb, 0);
      if (pq) qv[baseq + (unsigned int)__popcll(mq & ((1ull << lane) - 1ull))] = v;
      if (pb) {
        unsigned int p = baseb + (unsigned int)__popcll(mb & ((1ull << lane) - 1ull));
        if (p < 12288u) buf[p] = key;
      }
    }
  }
  __syncthreads();
  int ncand = (int)cnts[1];
  bool stored = (ncand <= 12288);

  // P3: three byte-level radix passes for exact threshold key
  unsigned int prefix = B0 << 24;
  for (int level = 0; level < 3; ++level) {
    int shift = 16 - level * 8;
    if (tid < 256) histL[tid] = 0u;
    __syncthreads();
    unsigned int myk[12];             // statically indexed (registers)
    if (stored) {
#pragma unroll
      for (int k = 0; k < 12; ++k) {
        int i = tid + (k << 10);
        if (i < ncand) myk[k] = buf[i];
      }
      __syncthreads();   // all reads done before buf rewrite
#pragma unroll
      for (int k = 0; k < 12; ++k) {
        int i = tid + (k << 10);
        if (i < ncand) atomicAdd(&histL[(myk[k] >> shift) & 255u], 1u);
      }
    } else {
      unsigned int hiMask = 0xFFFFFFFFu << (shift + 8);
      for (int j = tid; j < 20000; j += 1024) {
        int c = j / 1000;
        if (c == clsRow) continue;
        unsigned int key = f2key(row[j]);
        if ((key & hiMask) == prefix) atomicAdd(&histL[(key >> shift) & 255u], 1u);
      }
    }
    __syncthreads();
    suffix_select(histL, sfx, cnts, tid, krem);
    unsigned int bk = cnts[3];
    unsigned int above = sfx[bk + 1];
    krem -= above;
    prefix |= bk << shift;
    if (stored) {
      __syncthreads();
      if (tid == 0) cnts[4] = 0u;
      __syncthreads();
#pragma unroll
      for (int k = 0; k < 12; ++k) {
        int i = tid + (k << 10);
        if (i < ncand) {
          unsigned int b = (myk[k] >> shift) & 255u;
          if (b > bk) qv[atomicAdd(&cnts[2], 1u)] = key2f(myk[k]);
          else if (b == bk) buf[atomicAdd(&cnts[4], 1u)] = myk[k];
        }
      }
      __syncthreads();
      ncand = (int)cnts[4];
    }
  }
  float tval = key2f(prefix);

  if (!stored) {   // fallback: gather all > threshold within bucket B0 from global
    for (int j = tid; j < 20000; j += 1024) {
      int c = j / 1000;
      if (c == clsRow) continue;
      float v = row[j];
      unsigned int key = f2key(v);
      if ((key >> 24) == B0 && key > prefix) qv[atomicAdd(&cnts[2], 1u) & 1023u] = v;
    }
    __syncthreads();
  }
  int qn = (int)cnts[2];          // strictly-greater count, <= 999
  float tieW = (float)krem;       // == 1000 - qn copies of tval

  // P4: one negative per thread; sum relu(pos + margin - neg) over 1024-padded pos
  float v, w;
  if (tid < qn)       { v = qv[tid]; w = 1.f; }
  else if (tid == qn) { v = tval;    w = tieW; }
  else                { v = 0.f;     w = 0.f; }
  float t = v - MARGINF;
  float s0 = 0.f, s1 = 0.f, s2 = 0.f, s3 = 0.f;
  if (w != 0.f) {
    for (int pc = 0; pc < 1024; pc += 16) {
      float4 p0 = *(const float4*)&posArr[pc];
      float4 p1 = *(const float4*)&posArr[pc + 4];
      float4 p2 = *(const float4*)&posArr[pc + 8];
      float4 p3 = *(const float4*)&posArr[pc + 12];
      s0 += fmaxf(p0.x - t, 0.f); s1 += fmaxf(p0.y - t, 0.f);
      s2 += fmaxf(p0.z - t, 0.f); s3 += fmaxf(p0.w - t, 0.f);
      s0 += fmaxf(p1.x - t, 0.f); s1 += fmaxf(p1.y - t, 0.f);
      s2 += fmaxf(p1.z - t, 0.f); s3 += fmaxf(p1.w - t, 0.f);
      s0 += fmaxf(p2.x - t, 0.f); s1 += fmaxf(p2.y - t, 0.f);
      s2 += fmaxf(p2.z - t, 0.f); s3 += fmaxf(p2.w - t, 0.f);
      s0 += fmaxf(p3.x - t, 0.f); s1 += fmaxf(p3.y - t, 0.f);
      s2 += fmaxf(p3.z - t, 0.f); s3 += fmaxf(p3.w - t, 0.f);
    }
  }
  float local = w * ((s0 + s1) + (s2 + s3));
  for (int off = 32; off; off >>= 1) local += __shfl_down(local, off);
  if (lane == 0) fred[wid] = local;
  __syncthreads();
  if (tid == 0) {
    float s = 0.f;
#pragma unroll
    for (int i = 0; i < 16; ++i) s += fred[i];
    per_anchor[a] = s * 1e-6f;
    __threadfence();
    unsigned int tk = atomicAdd((unsigned int*)&hdr[6], 1u);
    lastFlag = (tk == (unsigned int)(nv - 1)) ? 1u : 0u;
  }
  __syncthreads();
  if (lastFlag) {
    __threadfence();   // acquire: all blocks' per_anchor stores visible
    float s = (tid < nv) ? per_anchor[tid] : 0.f;
    for (int off = 32; off; off >>= 1) s += __shfl_down(s, off);
    if (lane == 0) fred[wid] = s;
    __syncthreads();
    if (tid == 0) {
      float tot = 0.f;
#pragma unroll
      for (int i = 0; i < 16; ++i) tot += fred[i];
      out[0] = tot / (float)max(nv, 1);
    }
  }
}

// fallback-only: new_memory writer + nv==0 loss shim (small-ws chunked path)
__global__ void k_writemem(const float* __restrict__ memory, const float* __restrict__ anchors,
                           const int* __restrict__ hdr, float* __restrict__ out) {
  int cls = hdr[0], nv = hdr[5];
  if (nv == 0 && blockIdx.x == 0 && threadIdx.x == 0) out[0] = 0.f;
  int i = blockIdx.x * 1024 + threadIdx.x;
#pragma unroll
  for (int k = 0; k < 4; ++k, i += 256) {
    float v = memory[i];
    int c = i / 128000;
    int rem = i - c * 128000;
    int m = rem >> 7, d = rem & 127;
    if (cls >= 1 && cls <= 20 && c == cls - 1 && m < nv) v = anchors[m * 128 + d];
    out[1 + i] = v;
  }
}

extern "C" void kernel_launch(void* const* d_in, const int* in_sizes, int n_in,
                              void* d_out, int out_size, void* d_ws, size_t ws_size,
                              hipStream_t stream) {
  const float* preds  = (const float*)d_in[0];
  const float* emb    = (const float*)d_in[1];
  const int*   wsss   = (const int*)d_in[2];
  const int*   fsss   = (const int*)d_in[3];
  const float* memory = (const float*)d_in[4];
  float* out = (float*)d_out;
  char* ws = (char*)d_ws;
  int* hdr = (int*)ws;
  int* easy_idx = (int*)(ws + OFF_EASY);
  int* hard_idx = (int*)(ws + OFF_HARD);
  float* per_anchor = (float*)(ws + OFF_PERA);
  int* minArr = (int*)(ws + OFF_MINARR);
  unsigned short* fl = (unsigned short*)(ws + OFF_FL);
  float* anchors = (float*)(ws + OFF_ANCH);
  float* sims = (float*)(ws + OFF_SIMS);

  hipLaunchKernelGGL(k_prep, dim3(512), dim3(256),  0, stream, wsss, fsss, preds, fl, minArr);
  hipLaunchKernelGGL(k_pa,   dim3(1),   dim3(1024), 0, stream, fl, minArr, hdr,
                     easy_idx, hard_idx, emb, anchors);

  long long avail = (long long)ws_size - (long long)OFF_SIMS;
  int capWs = (avail > 0) ? (int)(avail / 80000LL) : 0;
  if (capWs > A_TOT) capWs = A_TOT;

  if (capWs >= A_TOT) {
    // fast path: 4 dispatches total (prep, pa, sims, topk)
    dim3 gs(313, (A_TOT + 63) / 64);
    hipLaunchKernelGGL(k_sims, gs, dim3(256), 0, stream, anchors, memory, sims, 0, A_TOT);
    hipLaunchKernelGGL(k_topk, dim3(A_TOT), dim3(1024), 0, stream, sims, hdr, per_anchor,
                       0, A_TOT, out, memory, anchors, 1);
  } else {
    // fallback: chunked sims via out-buffer scratch (out+4, 16B-aligned)
    float* outScr = out + 4;
    int capOut = (int)(((long long)out_size / 4 - 4) / 20000LL);
    if (capOut > 127) capOut = 127;
    if (capOut < 0) capOut = 0;
    if (capOut + capWs < 1) capWs = 1;
    int aoff = 0;
    while (aoff < A_TOT) {
      int nOut = A_TOT - aoff; if (nOut > capOut) nOut = capOut;
      int nWs  = A_TOT - aoff - nOut; if (nWs > capWs) nWs = capWs;
      if (nOut > 0) {
        dim3 g1(313, (nOut + 63) / 64);
        hipLaunchKernelGGL(k_sims, g1, dim3(256), 0, stream, anchors, memory, outScr, aoff, nOut);
      }
      if (nWs > 0) {
        dim3 g2(313, (nWs + 63) / 64);
        hipLaunchKernelGGL(k_sims, g2, dim3(256), 0, stream, anchors, memory, sims, aoff + nOut, nWs);
      }
      if (nOut > 0)
        hipLaunchKernelGGL(k_topk, dim3(nOut), dim3(1024), 0, stream, outScr, hdr, per_anchor,
                           aoff, nOut, out, memory, anchors, 0);
      if (nWs > 0)
        hipLaunchKernelGGL(k_topk, dim3(nWs), dim3(1024), 0, stream, sims, hdr, per_anchor,
                           aoff + nOut, nWs, out, memory, anchors, 0);
      aoff += nOut + nWs;
    }
    hipLaunchKernelGGL(k_writemem, dim3(2500), dim3(256), 0, stream, memory, anchors, hdr, out);
  }
}

// Round 10
// 369.991 us; speedup vs baseline: 1.5410x; 1.1387x over previous
//
#include <hip/hip_runtime.h>
#include <stdint.h>

#define NCK 21
// reference: K_EASY = int(200*(1-0.8)) = int(39.9999...) = 39 (Python float trunc!)
#define K_EASY 39
#define K_HARD 160
#define A_TOT  199
#define MARGINF 0.2f

// ws byte offsets
#define OFF_EASY   64
#define OFF_HARD   256
#define OFF_PERA   1024
#define OFF_MINARR 2048
#define OFF_FLAGS1 4096
#define OFF_FLAGS2 135168
#define OFF_ANCH   266240
#define OFF_SIMS   409600

__device__ __forceinline__ unsigned int f2key(float f) {
  unsigned int u = __float_as_uint(f);
  return u ^ ((u & 0x80000000u) ? 0xFFFFFFFFu : 0x80000000u);
}
__device__ __forceinline__ float key2f(unsigned int k) {
  unsigned int u = (k & 0x80000000u) ? (k ^ 0x80000000u) : (k ^ 0xFFFFFFFFu);
  return __uint_as_float(u);
}

// K1: downsampled label/fg byte per pixel + per-block min class -> minArr
__global__ void k_prep(const int* __restrict__ wsss, const int* __restrict__ fsss,
                       unsigned char* __restrict__ flags1, int* __restrict__ minArr) {
  int p = blockIdx.x * 256 + threadIdx.x;           // 0..131071
  int b = p >> 14, r = p & 16383, i = r >> 7, j = r & 127;
  int gi = (b * 512 + i * 4) * 512 + j * 4;
  int w = wsss[gi];
  int f = fsss[gi];
  int fg = (f != 0 && f != 255) ? 1 : 0;
  int wl = (w != 0 && w != 255) ? 1 : 0;
  flags1[p] = (unsigned char)((w & 63) | (fg << 6));
  int cand = wl ? w : NCK;
  for (int off = 32; off > 0; off >>= 1) cand = min(cand, __shfl_down(cand, off));
  __shared__ int wmin[4];
  int lane = threadIdx.x & 63, wid = threadIdx.x >> 6;
  if (lane == 0) wmin[wid] = cand;
  __syncthreads();
  if (threadIdx.x == 0)
    minArr[blockIdx.x] = min(min(wmin[0], wmin[1]), min(wmin[2], wmin[3]));
}

// K2: easy/hard flags. Each block re-reduces minArr (kernel-boundary-ordered,
// L2-hot). Block 0 publishes hdr[0]=cls and resets the loss ticket hdr[6].
__global__ void k_flags(const float* __restrict__ preds, const unsigned char* __restrict__ flags1,
                        unsigned char* __restrict__ flags2, const int* __restrict__ minArr,
                        int* __restrict__ hdr) {
  int tid = threadIdx.x;
  __shared__ int wm[4];
  __shared__ int s_cls;
  int m = min(minArr[tid], minArr[tid + 256]);
  for (int off = 32; off > 0; off >>= 1) m = min(m, __shfl_down(m, off));
  int lane = tid & 63, wid = tid >> 6;
  if (lane == 0) wm[wid] = m;
  __syncthreads();
  if (tid == 0) {
    int c = min(min(wm[0], wm[1]), min(wm[2], wm[3]));
    s_cls = c;
    if (blockIdx.x == 0) { hdr[0] = c; hdr[6] = 0; }
  }
  __syncthreads();
  int cls = s_cls;
  int p = blockIdx.x * 256 + tid;
  unsigned char f1 = flags1[p];
  unsigned char out = 0;
  if ((f1 & 64) && (int)(f1 & 63) == cls) {
    int b = p >> 14, r = p & 16383, i = r >> 7, j = r & 127;
    int base = ((b * NCK) * 512 + i * 4) * 512 + j * 4;
    float best = preds[base]; int bi = 0;
#pragma unroll
    for (int ch = 1; ch < NCK; ++ch) {
      float v = preds[base + ch * 262144];
      if (v > best) { best = v; bi = ch; }
    }
    out = (bi == cls) ? 1 : 2;
  }
  flags2[p] = out;
}

// K3: ordered selection of first 39 easy / 160 hard indices (single wave).
// 4 chunks prefetched per iteration so global-load latencies overlap.
__global__ void k_pick(const unsigned char* __restrict__ flags2, int* __restrict__ hdr,
                       int* __restrict__ easy_idx, int* __restrict__ hard_idx) {
  int lane = threadIdx.x;  // 0..63
  const unsigned long long* f8 = (const unsigned long long*)flags2;
  unsigned int runE = 0, runH = 0;
  for (int it4 = 0; it4 < 64; ++it4) {    // 64 * 4 * 64 lanes * 8 bytes = 131072
    unsigned long long vv0 = f8[(it4 * 4 + 0) * 64 + lane];
    unsigned long long vv1 = f8[(it4 * 4 + 1) * 64 + lane];
    unsigned long long vv2 = f8[(it4 * 4 + 2) * 64 + lane];
    unsigned long long vv3 = f8[(it4 * 4 + 3) * 64 + lane];
#pragma unroll
    for (int q = 0; q < 4; ++q) {
      unsigned long long v = (q == 0) ? vv0 : (q == 1) ? vv1 : (q == 2) ? vv2 : vv3;
      int it = it4 * 4 + q;
      unsigned int e = 0, h = 0;
#pragma unroll
      for (int g = 0; g < 8; ++g) {
        unsigned int b = (unsigned int)((v >> (8 * g)) & 255ull);
        e += (b == 1u); h += (b == 2u);
      }
      unsigned int x = (e << 16) | h;
      unsigned int incl = x;
#pragma unroll
      for (int off = 1; off < 64; off <<= 1) {
        unsigned int t = __shfl_up(incl, off);
        if (lane >= off) incl += t;
      }
      unsigned int excl = incl - x;
      unsigned int eRk = runE + (excl >> 16);
      unsigned int hRk = runH + (excl & 0xFFFFu);
#pragma unroll
      for (int g = 0; g < 8; ++g) {
        unsigned int b = (unsigned int)((v >> (8 * g)) & 255ull);
        int p = it * 512 + lane * 8 + g;
        if (b == 1u)      { if (eRk < K_EASY) easy_idx[eRk] = p; eRk++; }
        else if (b == 2u) { if (hRk < K_HARD) hard_idx[hRk] = p; hRk++; }
      }
      unsigned int tot = __shfl(incl, 63);
      runE += (tot >> 16); runH += (tot & 0xFFFFu);
    }
    if (runE >= K_EASY && runH >= K_HARD) break;   // uniform
  }
  if (lane == 0) {
    int neU = runE < K_EASY ? (int)runE : K_EASY;
    int nhU = runH < K_HARD ? (int)runH : K_HARD;
    hdr[1] = (int)runE; hdr[2] = (int)runH;
    hdr[3] = neU; hdr[4] = nhU; hdr[5] = neU + nhU;
  }
}

// K4: gather + normalize anchor embeddings (pad to 256 rows with zeros)
__global__ void k_anchors(const float* __restrict__ emb, const int* __restrict__ hdr,
                          const int* __restrict__ easy_idx, const int* __restrict__ hard_idx,
                          float* __restrict__ anchors) {
  int a = blockIdx.x;        // 0..255
  int tid = threadIdx.x;     // 64
  int nv = hdr[5], neU = hdr[3];
  float v0 = 0.f, v1 = 0.f;
  if (a < nv) {
    int p = (a < neU) ? easy_idx[a] : hard_idx[a - neU];
    int b = p >> 14, r = p & 16383, i = r >> 7, j = r & 127;
    int base = b * 2097152 + i * 128 + j;
    v0 = emb[base + tid * 16384];
    v1 = emb[base + (tid + 64) * 16384];
  }
  float ss = v0 * v0 + v1 * v1;
  for (int off = 32; off > 0; off >>= 1) ss += __shfl_xor(ss, off);
  float inv = 1.0f / fmaxf(sqrtf(ss), 1e-12f);
  anchors[a * 128 + tid] = v0 * inv;
  anchors[a * 128 + tid + 64] = v1 * inv;
}

// K5: sims[la][cm] = dot(anchor_{a0+la}, mem_row_cm) * invnorm(mem_row). 64x64 tiles.
__global__ __launch_bounds__(256) void k_sims(const float* __restrict__ anchors,
                       const float* __restrict__ memory, float* __restrict__ sims,
                       int a0, int ac) {
  __shared__ float As[64 * 128];
  __shared__ float Ms[64 * 128];
  int mT = blockIdx.x, aT = blockIdx.y;
  int aBase = aT * 64, mBase = mT * 64;
  int tid = threadIdx.x;
#pragma unroll
  for (int k = 0; k < 8; ++k) {   // stage A (swizzled 16B chunks)
    int f4i = tid + k * 256;
    int row = f4i >> 5, c = f4i & 31;
    int gR = a0 + aBase + row; if (gR > 255) gR = 255;
    float4 v = ((const float4*)anchors)[gR * 32 + c];
    *(float4*)&As[row * 128 + ((c ^ (row & 31)) << 2)] = v;
  }
#pragma unroll
  for (int k = 0; k < 8; ++k) {   // stage M
    int f4i = tid + k * 256;
    int row = f4i >> 5, c = f4i & 31;
    int grow = mBase + row;
    float4 v = make_float4(0.f, 0.f, 0.f, 0.f);
    if (grow < 20000) v = ((const float4*)memory)[grow * 32 + c];
    *(float4*)&Ms[row * 128 + ((c ^ (row & 31)) << 2)] = v;
  }
  __syncthreads();
  int tx = tid & 15, ty = tid >> 4;
  float acc[4][4];
#pragma unroll
  for (int i = 0; i < 4; ++i)
#pragma unroll
    for (int j = 0; j < 4; ++j) acc[i][j] = 0.f;
#pragma unroll 2
  for (int c = 0; c < 32; ++c) {
    float4 av[4], mv[4];
#pragma unroll
    for (int i = 0; i < 4; ++i) {
      int ar = ty + 16 * i;
      av[i] = *(const float4*)&As[ar * 128 + ((c ^ (ar & 31)) << 2)];
    }
#pragma unroll
    for (int j = 0; j < 4; ++j) {
      int mr = tx + 16 * j;
      mv[j] = *(const float4*)&Ms[mr * 128 + ((c ^ (mr & 31)) << 2)];
    }
#pragma unroll
    for (int i = 0; i < 4; ++i)
#pragma unroll
      for (int j = 0; j < 4; ++j)
        acc[i][j] += av[i].x * mv[j].x + av[i].y * mv[j].y + av[i].z * mv[j].z + av[i].w * mv[j].w;
  }
  __syncthreads();
  {
    int row = tid >> 2, q = tid & 3;
    float ss = 0.f;
#pragma unroll
    for (int k = 0; k < 8; ++k) {
      float4 v = *(const float4*)&Ms[row * 128 + q * 32 + k * 4];
      ss += v.x * v.x + v.y * v.y + v.z * v.z + v.w * v.w;
    }
    ss += __shfl_down(ss, 2, 4);
    ss += __shfl_down(ss, 1, 4);
    if (q == 0) As[row] = 1.0f / fmaxf(sqrtf(ss), 1e-8f);
  }
  __syncthreads();
#pragma unroll
  for (int i = 0; i < 4; ++i) {
    int la = aBase + ty + 16 * i;
    if (la < ac) {
#pragma unroll
      for (int j = 0; j < 4; ++j) {
        int m = mBase + tx + 16 * j;
        if (m < 20000) sims[(size_t)la * 20000 + m] = acc[i][j] * As[tx + 16 * j];
      }
    }
  }
}

// 256-bin suffix-sum + boundary select (wave-0-only, ONE barrier).
__device__ __forceinline__ void suffix_select(unsigned int* histL, unsigned int* sfx,
                                              unsigned int* cnts, int tid, unsigned int krem) {
  if (tid < 64) {
    int lane = tid;
    unsigned int h0 = histL[lane * 4 + 0];
    unsigned int h1 = histL[lane * 4 + 1];
    unsigned int h2 = histL[lane * 4 + 2];
    unsigned int h3 = histL[lane * 4 + 3];
    unsigned int s = h0 + h1 + h2 + h3;
    unsigned int incl = s;                        // sum over lanes >= lane
#pragma unroll
    for (int off = 1; off < 64; off <<= 1) {
      unsigned int t = __shfl_down(incl, off);
      if (lane + off < 64) incl += t;
    }
    unsigned int above = incl - s;                // sum over lanes > lane
    unsigned int f3 = above + h3;
    unsigned int f2 = f3 + h2;
    unsigned int f1 = f2 + h1;
    unsigned int f0 = f1 + h0;
    sfx[lane * 4 + 0] = f0; sfx[lane * 4 + 1] = f1;
    sfx[lane * 4 + 2] = f2; sfx[lane * 4 + 3] = f3;
    if (lane == 63) sfx[256] = 0u;
    if (f0 >= krem && f1 < krem)    cnts[3] = (unsigned int)(lane * 4 + 0);
    if (f1 >= krem && f2 < krem)    cnts[3] = (unsigned int)(lane * 4 + 1);
    if (f2 >= krem && f3 < krem)    cnts[3] = (unsigned int)(lane * 4 + 2);
    if (f3 >= krem && above < krem) cnts[3] = (unsigned int)(lane * 4 + 3);
  }
  __syncthreads();
}

// K6: per-anchor exact top-1000 negatives + pair-loss. 1024 threads (16 waves).
// Fused: (a) doCopy -> grid-strided new_memory write; (b) last-finisher ticket
// on hdr[6] reduces per_anchor -> out[0].
__global__ __launch_bounds__(1024) void k_topk(const float* __restrict__ sims,
                       int* __restrict__ hdr, float* __restrict__ per_anchor,
                       int a0, int ac, float* __restrict__ out,
                       const float* __restrict__ memory, const float* __restrict__ anchors,
                       int doCopy) {
  int tid = threadIdx.x, lane = tid & 63, wid = tid >> 6;
  int nv = hdr[5];
  int cls = hdr[0];

  if (doCopy) {   // fused k_writemem: runs on every block, before any early-out
    int step = gridDim.x * 1024;
    for (int i = blockIdx.x * 1024 + tid; i < 2560000; i += step) {
      float v = memory[i];
      int c = i / 128000;
      int rem = i - c * 128000;
      int m = rem >> 7, d = rem & 127;
      if (cls >= 1 && cls <= 20 && c == cls - 1 && m < nv) v = anchors[m * 128 + d];
      out[1 + i] = v;
    }
    if (nv == 0 && blockIdx.x == 0 && tid == 0) out[0] = 0.f;
  }

  int la = blockIdx.x;
  if (la >= ac) return;
  int a = a0 + la;
  if (a >= nv) return;
  int clsRow = cls - 1;

  __shared__ float posArr[1024];
  __shared__ float qv[1024];
  __shared__ unsigned int hist16[16][256];
  __shared__ unsigned int histL[256];
  __shared__ unsigned int sfx[257];
  __shared__ unsigned int buf[12288];
  __shared__ unsigned int cnts[8];  // 1:bufCnt 2:qvCnt 3:sel 4:levelBufCnt
  __shared__ float fred[16];
  __shared__ unsigned int lastFlag;

  const float* row = sims + (size_t)la * 20000;   // 16B-aligned

  // init
  for (int i = tid; i < 16 * 256; i += 1024) ((unsigned int*)hist16)[i] = 0u;
  if (tid < 24) posArr[1000 + tid] = -1e30f;
  if (tid < 8) cnts[tid] = 0u;
  __syncthreads();

  // P1: per-wave histograms of neg keys' top byte; stash pos row.
  float4 rowq[5];
#pragma unroll
  for (int k = 0; k < 5; ++k) {
    int j = (k << 12) + (tid << 2);
    float4 v = make_float4(0.f, 0.f, 0.f, 0.f);
    if (j < 20000) v = *(const float4*)&row[j];
    rowq[k] = v;
  }
#pragma unroll
  for (int k = 0; k < 5; ++k) {
    int j = (k << 12) + (tid << 2);
    if (j < 20000) {
      int c = j / 1000;
      float4 v = rowq[k];
      if (c == clsRow) {
        *(float4*)&posArr[j - clsRow * 1000] = v;
      } else {
        atomicAdd(&hist16[wid][f2key(v.x) >> 24], 1u);
        atomicAdd(&hist16[wid][f2key(v.y) >> 24], 1u);
        atomicAdd(&hist16[wid][f2key(v.z) >> 24], 1u);
        atomicAdd(&hist16[wid][f2key(v.w) >> 24], 1u);
      }
    }
  }
  __syncthreads();
  if (tid < 256) {
    unsigned int s = 0;
#pragma unroll
    for (int w = 0; w < 16; ++w) s += hist16[w][tid];
    histL[tid] = s;
  }
  __syncthreads();
  suffix_select(histL, sfx, cnts, tid, 1000u);
  unsigned int B0 = cnts[3];
  unsigned int krem = 1000u - sfx[B0 + 1];   // slots to fill from bucket B0
  __syncthreads();

  // P2: compact from registers. top-byte > B0 -> qv; == B0 -> key buf
#pragma unroll
  for (int k = 0; k < 5; ++k) {
    int j = (k << 12) + (tid << 2);
    bool inb = (j < 20000);
    int c = inb ? (j / 1000) : -1;
    bool neg = inb && (c != clsRow);
    float4 v4 = rowq[k];
#pragma unroll
    for (int e = 0; e < 4; ++e) {
      float v = (e == 0) ? v4.x : (e == 1) ? v4.y : (e == 2) ? v4.z : v4.w;
      unsigned int key = f2key(v);
      unsigned int tb = key >> 24;
      bool pq = neg && (tb > B0);
      bool pb = neg && (tb == B0);
      unsigned long long mq = __ballot(pq);
      unsigned long long mb = __ballot(pb);
      unsigned int baseq = 0u, baseb = 0u;
      if (lane == 0) {
        if (mq) baseq = atomicAdd(&cnts[2], (unsigned int)__popcll(mq));
        if (mb) baseb = atomicAdd(&cnts[1], (unsigned int)__popcll(mb));
      }
      baseq = __shfl(baseq, 0); baseb = __shfl(baseb, 0);
      if (pq) qv[baseq + (unsigned int)__popcll(mq & ((1ull << lane) - 1ull))] = v;
      if (pb) {
        unsigned int p = baseb + (unsigned int)__popcll(mb & ((1ull << lane) - 1ull));
        if (p < 12288u) buf[p] = key;
      }
    }
  }
  __syncthreads();
  int ncand = (int)cnts[1];
  bool stored = (ncand <= 12288);

  // P3: three byte-level radix passes for exact threshold key
  unsigned int prefix = B0 << 24;
  for (int level = 0; level < 3; ++level) {
    int shift = 16 - level * 8;
    if (tid < 256) histL[tid] = 0u;
    __syncthreads();
    unsigned int myk[12];             // statically indexed (registers)
    if (stored) {
#pragma unroll
      for (int k = 0; k < 12; ++k) {
        int i = tid + (k << 10);
        if (i < ncand) myk[k] = buf[i];
      }
      __syncthreads();   // all reads done before buf rewrite
#pragma unroll
      for (int k = 0; k < 12; ++k) {
        int i = tid + (k << 10);
        if (i < ncand) atomicAdd(&histL[(myk[k] >> shift) & 255u], 1u);
      }
    } else {
      unsigned int hiMask = 0xFFFFFFFFu << (shift + 8);
      for (int j = tid; j < 20000; j += 1024) {
        int c = j / 1000;
        if (c == clsRow) continue;
        unsigned int key = f2key(row[j]);
        if ((key & hiMask) == prefix) atomicAdd(&histL[(key >> shift) & 255u], 1u);
      }
    }
    __syncthreads();
    suffix_select(histL, sfx, cnts, tid, krem);
    unsigned int bk = cnts[3];
    unsigned int above = sfx[bk + 1];
    krem -= above;
    prefix |= bk << shift;
    if (stored) {
      __syncthreads();
      if (tid == 0) cnts[4] = 0u;
      __syncthreads();
#pragma unroll
      for (int k = 0; k < 12; ++k) {
        int i = tid + (k << 10);
        if (i < ncand) {
          unsigned int b = (myk[k] >> shift) & 255u;
          if (b > bk) qv[atomicAdd(&cnts[2], 1u)] = key2f(myk[k]);
          else if (b == bk) buf[atomicAdd(&cnts[4], 1u)] = myk[k];
        }
      }
      __syncthreads();
      ncand = (int)cnts[4];
    }
  }
  float tval = key2f(prefix);

  if (!stored) {   // fallback: gather all > threshold within bucket B0 from global
    for (int j = tid; j < 20000; j += 1024) {
      int c = j / 1000;
      if (c == clsRow) continue;
      float v = row[j];
      unsigned int key = f2key(v);
      if ((key >> 24) == B0 && key > prefix) qv[atomicAdd(&cnts[2], 1u) & 1023u] = v;
    }
    __syncthreads();
  }
  int qn = (int)cnts[2];          // strictly-greater count, <= 999
  float tieW = (float)krem;       // == 1000 - qn copies of tval

  // P4: one negative per thread; sum relu(pos + margin - neg) over 1024-padded pos
  float v, w;
  if (tid < qn)       { v = qv[tid]; w = 1.f; }
  else if (tid == qn) { v = tval;    w = tieW; }
  else                { v = 0.f;     w = 0.f; }
  float t = v - MARGINF;
  float s0 = 0.f, s1 = 0.f, s2 = 0.f, s3 = 0.f;
  if (w != 0.f) {
    for (int pc = 0; pc < 1024; pc += 16) {
      float4 p0 = *(const float4*)&posArr[pc];
      float4 p1 = *(const float4*)&posArr[pc + 4];
      float4 p2 = *(const float4*)&posArr[pc + 8];
      float4 p3 = *(const float4*)&posArr[pc + 12];
      s0 += fmaxf(p0.x - t, 0.f); s1 += fmaxf(p0.y - t, 0.f);
      s2 += fmaxf(p0.z - t, 0.f); s3 += fmaxf(p0.w - t, 0.f);
      s0 += fmaxf(p1.x - t, 0.f); s1 += fmaxf(p1.y - t, 0.f);
      s2 += fmaxf(p1.z - t, 0.f); s3 += fmaxf(p1.w - t, 0.f);
      s0 += fmaxf(p2.x - t, 0.f); s1 += fmaxf(p2.y - t, 0.f);
      s2 += fmaxf(p2.z - t, 0.f); s3 += fmaxf(p2.w - t, 0.f);
      s0 += fmaxf(p3.x - t, 0.f); s1 += fmaxf(p3.y - t, 0.f);
      s2 += fmaxf(p3.z - t, 0.f); s3 += fmaxf(p3.w - t, 0.f);
    }
  }
  float local = w * ((s0 + s1) + (s2 + s3));
  for (int off = 32; off; off >>= 1) local += __shfl_down(local, off);
  if (lane == 0) fred[wid] = local;
  __syncthreads();
  if (tid == 0) {
    float s = 0.f;
#pragma unroll
    for (int i = 0; i < 16; ++i) s += fred[i];
    per_anchor[a] = s * 1e-6f;
    __threadfence();
    unsigned int tk = atomicAdd((unsigned int*)&hdr[6], 1u);
    lastFlag = (tk == (unsigned int)(nv - 1)) ? 1u : 0u;
  }
  __syncthreads();
  if (lastFlag) {
    __threadfence();   // acquire: all blocks' per_anchor stores visible
    float s = (tid < nv) ? per_anchor[tid] : 0.f;
    for (int off = 32; off; off >>= 1) s += __shfl_down(s, off);
    if (lane == 0) fred[wid] = s;
    __syncthreads();
    if (tid == 0) {
      float tot = 0.f;
#pragma unroll
      for (int i = 0; i < 16; ++i) tot += fred[i];
      out[0] = tot / (float)max(nv, 1);
    }
  }
}

// fallback-only: new_memory writer + nv==0 loss shim (small-ws chunked path)
__global__ void k_writemem(const float* __restrict__ memory, const float* __restrict__ anchors,
                           const int* __restrict__ hdr, float* __restrict__ out) {
  int cls = hdr[0], nv = hdr[5];
  if (nv == 0 && blockIdx.x == 0 && threadIdx.x == 0) out[0] = 0.f;
  int i = blockIdx.x * 1024 + threadIdx.x;
#pragma unroll
  for (int k = 0; k < 4; ++k, i += 256) {
    float v = memory[i];
    int c = i / 128000;
    int rem = i - c * 128000;
    int m = rem >> 7, d = rem & 127;
    if (cls >= 1 && cls <= 20 && c == cls - 1 && m < nv) v = anchors[m * 128 + d];
    out[1 + i] = v;
  }
}

extern "C" void kernel_launch(void* const* d_in, const int* in_sizes, int n_in,
                              void* d_out, int out_size, void* d_ws, size_t ws_size,
                              hipStream_t stream) {
  const float* preds  = (const float*)d_in[0];
  const float* emb    = (const float*)d_in[1];
  const int*   wsss   = (const int*)d_in[2];
  const int*   fsss   = (const int*)d_in[3];
  const float* memory = (const float*)d_in[4];
  float* out = (float*)d_out;
  char* ws = (char*)d_ws;
  int* hdr = (int*)ws;
  int* easy_idx = (int*)(ws + OFF_EASY);
  int* hard_idx = (int*)(ws + OFF_HARD);
  float* per_anchor = (float*)(ws + OFF_PERA);
  int* minArr = (int*)(ws + OFF_MINARR);
  unsigned char* flags1 = (unsigned char*)(ws + OFF_FLAGS1);
  unsigned char* flags2 = (unsigned char*)(ws + OFF_FLAGS2);
  float* anchors = (float*)(ws + OFF_ANCH);
  float* sims = (float*)(ws + OFF_SIMS);

  hipLaunchKernelGGL(k_prep,    dim3(512), dim3(256), 0, stream, wsss, fsss, flags1, minArr);
  hipLaunchKernelGGL(k_flags,   dim3(512), dim3(256), 0, stream, preds, flags1, flags2, minArr, hdr);
  hipLaunchKernelGGL(k_pick,    dim3(1),   dim3(64),  0, stream, flags2, hdr, easy_idx, hard_idx);
  hipLaunchKernelGGL(k_anchors, dim3(256), dim3(64),  0, stream, emb, hdr, easy_idx, hard_idx, anchors);

  // ws is large on this problem (~704 MB per round-2 fill counters) -> all 199 sims
  // rows fit in ws: ONE k_sims + ONE k_topk (fast path, 6 dispatches total; writemem
  // fused into k_topk). Chunked fallback (out+4 scratch) retained for small ws.
  long long avail = (long long)ws_size - (long long)OFF_SIMS;
  int capWs = (avail > 0) ? (int)(avail / 80000LL) : 0;
  if (capWs > A_TOT) capWs = A_TOT;

  if (capWs >= A_TOT) {
    dim3 gs(313, (A_TOT + 63) / 64);
    hipLaunchKernelGGL(k_sims, gs, dim3(256), 0, stream, anchors, memory, sims, 0, A_TOT);
    hipLaunchKernelGGL(k_topk, dim3(A_TOT), dim3(1024), 0, stream, sims, hdr, per_anchor,
                       0, A_TOT, out, memory, anchors, 1);
  } else {
    float* outScr = out + 4;
    int capOut = (int)(((long long)out_size / 4 - 4) / 20000LL);
    if (capOut > 127) capOut = 127;
    if (capOut < 0) capOut = 0;
    if (capOut + capWs < 1) capWs = 1;   // degenerate safety
    int aoff = 0;
    while (aoff < A_TOT) {
      int nOut = A_TOT - aoff; if (nOut > capOut) nOut = capOut;
      int nWs  = A_TOT - aoff - nOut; if (nWs > capWs) nWs = capWs;
      if (nOut > 0) {
        dim3 g1(313, (nOut + 63) / 64);
        hipLaunchKernelGGL(k_sims, g1, dim3(256), 0, stream, anchors, memory, outScr, aoff, nOut);
      }
      if (nWs > 0) {
        dim3 g2(313, (nWs + 63) / 64);
        hipLaunchKernelGGL(k_sims, g2, dim3(256), 0, stream, anchors, memory, sims, aoff + nOut, nWs);
      }
      if (nOut > 0)
        hipLaunchKernelGGL(k_topk, dim3(nOut), dim3(1024), 0, stream, outScr, hdr, per_anchor,
                           aoff, nOut, out, memory, anchors, 0);
      if (nWs > 0)
        hipLaunchKernelGGL(k_topk, dim3(nWs), dim3(1024), 0, stream, sims, hdr, per_anchor,
                           aoff + nOut, nWs, out, memory, anchors, 0);
      aoff += nOut + nWs;
    }
    hipLaunchKernelGGL(k_writemem, dim3(2500), dim3(256), 0, stream, memory, anchors, hdr, out);
  }
}